// Round 2
// baseline (87.703 us; speedup 1.0000x reference)
//
#include <hip/hip_runtime.h>
#include <hip/hip_bf16.h>

// Problem constants: P=512, K=4, D=256, N=4096. One block per id-group g,
// which owns rows {4g..4g+3} (half0) and {N/2+4g..N/2+4g+3} (half1). All 8
// rows' positive distances come from one 4x4 cross-half distance matrix.

// soft_rank (KL, strength=2) for a 4-vector of squared distances.
__device__ __forceinline__ void soft_rank4(const float d2[4], float r[4]) {
    float th[4]; int p[4] = {0, 1, 2, 3};
#pragma unroll
    for (int t = 0; t < 4; ++t) th[t] = 0.5f * sqrtf(fmaxf(d2[t], 1e-12f));
#define CSWAP(a, b)                                                           \
    if (th[a] < th[b]) {                                                      \
        float tt = th[a]; th[a] = th[b]; th[b] = tt;                          \
        int tp = p[a]; p[a] = p[b]; p[b] = tp;                                \
    }
    CSWAP(0, 1) CSWAP(1, 2) CSWAP(2, 3) CSWAP(0, 1) CSWAP(1, 2) CSWAP(0, 1)
#undef CSWAP
    const float logW[4][4] = {
        {1.3862944f, 1.9459101f, 2.1972246f, 2.3025851f},
        {0.f,        1.0986123f, 1.6094379f, 1.7917595f},
        {0.f,        0.f,        0.6931472f, 1.0986123f},
        {0.f,        0.f,        0.f,        0.f}};
    float B[4][4];
#pragma unroll
    for (int i = 0; i < 4; ++i) {
        float run = 0.f;
#pragma unroll
        for (int j = 0; j < 4; ++j) {
            if (j >= i) {
                run += __expf(th[j] - th[i]);
                B[i][j] = th[i] + __logf(run) - logW[i][j];
            }
        }
    }
    float rs[4];
#pragma unroll
    for (int k = 0; k < 4; ++k) {
        float dual = 1e30f;
#pragma unroll
        for (int i = 0; i < 4; ++i) {
            if (i <= k) {
                float mx = -1e30f;
#pragma unroll
                for (int j = 0; j < 4; ++j)
                    if (j >= k) mx = fmaxf(mx, B[i][j]);
                dual = fminf(dual, mx);
            }
        }
        rs[k] = __expf(th[k] - dual);
    }
#pragma unroll
    for (int t = 0; t < 4; ++t) {
        float v = rs[3];
        v = (p[2] == t) ? rs[2] : v;
        v = (p[1] == t) ? rs[1] : v;
        v = (p[0] == t) ? rs[0] : v;
        r[t] = v;
    }
}

__device__ __forceinline__ float spearman4(const float a[4], const float b[4]) {
    float ma = 0.25f * (a[0] + a[1] + a[2] + a[3]);
    float mb = 0.25f * (b[0] + b[1] + b[2] + b[3]);
    float sab = 0.f, saa = 0.f, sbb = 0.f;
#pragma unroll
    for (int t = 0; t < 4; ++t) {
        float x = a[t] - ma, y = b[t] - mb;
        sab += x * y; saa += x * x; sbb += y * y;
    }
    return sab * rsqrtf(saa * sbb);
}

__device__ __forceinline__ float row_loss(const float d2a[3][4]) {
    float ranks[3][4];
#pragma unroll
    for (int f = 0; f < 3; ++f) soft_rank4(d2a[f], ranks[f]);
    const float c01 = spearman4(ranks[0], ranks[1]);
    const float c02 = spearman4(ranks[0], ranks[2]);
    const float c12 = spearman4(ranks[1], ranks[2]);
    return (c01 + c02 + c12 + 3.f) * (0.5f / 3.f);
}

__global__ __launch_bounds__(256) void cmrr_fused(
        const float* __restrict__ f0, const float* __restrict__ f1,
        const float* __restrict__ f2, const int* __restrict__ target,
        float* __restrict__ ws, float* __restrict__ out, int N, float inv_n,
        int nblocks) {
    const float* F[3] = {f0, f1, f2};
    const int g = blockIdx.x;
    const int wave = threadIdx.x >> 6;
    const int lane = threadIdx.x & 63;
    const int half = N >> 1;

    __shared__ float4 stage[256];       // 4 half1 rows x 64 float4
    __shared__ float d2s[3][4][4];      // [feat][half0 row i][half1 row j]
    __shared__ float lsum[4];

    const int r0 = 4 * g + wave;        // this wave's half0 row
    const int id = target[4 * g];       // group id (uniform across waves)
    const int jbase = half + 4 * id;    // the 4 half1 rows of this group

#pragma unroll
    for (int f = 0; f < 3; ++f) {
        if (f) __syncthreads();         // protect stage reuse
        // cooperative stage of 4 contiguous half1 rows (4 KB, coalesced)
        stage[threadIdx.x] =
            ((const float4*)(F[f] + (size_t)jbase * 256))[threadIdx.x];
        __syncthreads();
        const float4 a = ((const float4*)(F[f] + (size_t)r0 * 256))[lane];
        float d2[4];
#pragma unroll
        for (int j = 0; j < 4; ++j) {
            const float4 b = stage[j * 64 + lane];
            const float dx = a.x - b.x, dy = a.y - b.y;
            const float dz = a.z - b.z, dw = a.w - b.w;
            float v = dx * dx + dy * dy + dz * dz + dw * dw;
#pragma unroll
            for (int m = 32; m >= 1; m >>= 1) v += __shfl_xor(v, m, 64);
            d2[j] = v;
        }
        if (lane == 0) {
#pragma unroll
            for (int j = 0; j < 4; ++j) d2s[f][wave][j] = d2[j];
        }
    }
    __syncthreads();

    // wave handles 2 rows: half0 row r0 (matrix row) and half1 row
    // jbase+wave (matrix column).
    float d2a[3][4], d2b[3][4];
#pragma unroll
    for (int f = 0; f < 3; ++f) {
#pragma unroll
        for (int t = 0; t < 4; ++t) {
            d2a[f][t] = d2s[f][wave][t];
            d2b[f][t] = d2s[f][t][wave];
        }
    }
    const float loss2 = row_loss(d2a) + row_loss(d2b);
    if (lane == 0) lsum[wave] = loss2;
    __syncthreads();

    if (threadIdx.x == 0) {
        const float partial = (lsum[0] + lsum[1]) + (lsum[2] + lsum[3]);
        atomicAdd(ws, partial);
        __threadfence();
        unsigned old = atomicAdd((unsigned*)(ws + 1), 1u);
        if (old == (unsigned)(nblocks - 1)) {
            const float total = atomicAdd(ws, 0.0f);  // L2-coherent read
            out[0] = total * inv_n;
        }
    }
}

extern "C" void kernel_launch(void* const* d_in, const int* in_sizes, int n_in,
                              void* d_out, int out_size, void* d_ws,
                              size_t ws_size, hipStream_t stream) {
    const float* f0 = (const float*)d_in[0];
    const float* f1 = (const float*)d_in[1];
    const float* f2 = (const float*)d_in[2];
    const int* target = (const int*)d_in[3];
    const int N = in_sizes[3];        // 4096
    const int nblocks = N / 8;        // one block per id-group (512)
    hipMemsetAsync(d_ws, 0, 16, stream);  // zero {acc, counter}
    cmrr_fused<<<nblocks, 256, 0, stream>>>(f0, f1, f2, target, (float*)d_ws,
                                            (float*)d_out, N, 1.0f / (float)N,
                                            nblocks);
}

// Round 3
// 86.053 us; speedup vs baseline: 1.0192x; 1.0192x over previous
//
#include <hip/hip_runtime.h>
#include <hip/hip_bf16.h>

// P=512, K=4, D=256, N=4096. One WAVE per id-group g: half0 rows 4g..4g+3,
// half1 rows N/2+4id..+3 (id=target[4g]==g). All 8 rows' positive distances
// are one 4x4 cross-half matrix d2[i][j]. Zero barriers, zero LDS.

__device__ __forceinline__ void soft_rank4(const float d2[4], float r[4]) {
    float th[4]; int p[4] = {0, 1, 2, 3};
#pragma unroll
    for (int t = 0; t < 4; ++t) th[t] = 0.5f * sqrtf(fmaxf(d2[t], 1e-12f));
#define CSWAP(a, b)                                                           \
    if (th[a] < th[b]) {                                                      \
        float tt = th[a]; th[a] = th[b]; th[b] = tt;                          \
        int tp = p[a]; p[a] = p[b]; p[b] = tp;                                \
    }
    CSWAP(0, 1) CSWAP(1, 2) CSWAP(2, 3) CSWAP(0, 1) CSWAP(1, 2) CSWAP(0, 1)
#undef CSWAP
    const float logW[4][4] = {
        {1.3862944f, 1.9459101f, 2.1972246f, 2.3025851f},
        {0.f,        1.0986123f, 1.6094379f, 1.7917595f},
        {0.f,        0.f,        0.6931472f, 1.0986123f},
        {0.f,        0.f,        0.f,        0.f}};
    float B[4][4];
#pragma unroll
    for (int i = 0; i < 4; ++i) {
        float run = 0.f;
#pragma unroll
        for (int j = 0; j < 4; ++j) {
            if (j >= i) {
                run += __expf(th[j] - th[i]);
                B[i][j] = th[i] + __logf(run) - logW[i][j];
            }
        }
    }
    float rs[4];
#pragma unroll
    for (int k = 0; k < 4; ++k) {
        float dual = 1e30f;
#pragma unroll
        for (int i = 0; i < 4; ++i) {
            if (i <= k) {
                float mx = -1e30f;
#pragma unroll
                for (int j = 0; j < 4; ++j)
                    if (j >= k) mx = fmaxf(mx, B[i][j]);
                dual = fminf(dual, mx);
            }
        }
        rs[k] = __expf(th[k] - dual);
    }
#pragma unroll
    for (int t = 0; t < 4; ++t) {
        float v = rs[3];
        v = (p[2] == t) ? rs[2] : v;
        v = (p[1] == t) ? rs[1] : v;
        v = (p[0] == t) ? rs[0] : v;
        r[t] = v;
    }
}

__device__ __forceinline__ float spearman4(const float a[4], const float b[4]) {
    float ma = 0.25f * (a[0] + a[1] + a[2] + a[3]);
    float mb = 0.25f * (b[0] + b[1] + b[2] + b[3]);
    float sab = 0.f, saa = 0.f, sbb = 0.f;
#pragma unroll
    for (int t = 0; t < 4; ++t) {
        float x = a[t] - ma, y = b[t] - mb;
        sab += x * y; saa += x * x; sbb += y * y;
    }
    return sab * rsqrtf(saa * sbb);
}

__device__ __forceinline__ float row_loss(const float d2a[3][4]) {
    float ranks[3][4];
#pragma unroll
    for (int f = 0; f < 3; ++f) soft_rank4(d2a[f], ranks[f]);
    const float c01 = spearman4(ranks[0], ranks[1]);
    const float c02 = spearman4(ranks[0], ranks[2]);
    const float c12 = spearman4(ranks[1], ranks[2]);
    return (c01 + c02 + c12 + 3.f) * (0.5f / 3.f);
}

__global__ __launch_bounds__(64) void cmrr_fused(
        const float* __restrict__ f0, const float* __restrict__ f1,
        const float* __restrict__ f2, const int* __restrict__ target,
        float* __restrict__ ws, float* __restrict__ out, int N, float inv_n,
        int nblocks) {
    const float* F[3] = {f0, f1, f2};
    const int g = blockIdx.x;
    const int lane = threadIdx.x;       // block == 1 wave
    const int half = N >> 1;
    const int id = target[4 * g];       // uniform -> scalar load
    const int jbase = half + 4 * id;

    // ---- 24 independent float4 loads: 8 rows x 3 features, lane = dim/4 ----
    float4 A[3][4], Bv[3][4];
#pragma unroll
    for (int f = 0; f < 3; ++f) {
        const float4* pa = (const float4*)(F[f] + (size_t)(4 * g) * 256);
#pragma unroll
        for (int i = 0; i < 4; ++i) A[f][i] = pa[i * 64 + lane];
    }
#pragma unroll
    for (int f = 0; f < 3; ++f) {
        const float4* pb = (const float4*)(F[f] + (size_t)jbase * 256);
#pragma unroll
        for (int j = 0; j < 4; ++j) Bv[f][j] = pb[j * 64 + lane];
    }

    // ---- 48 per-lane distance partials (value idx v = f*16 + i*4 + j) ----
    float c[64];
#pragma unroll
    for (int f = 0; f < 3; ++f) {
#pragma unroll
        for (int i = 0; i < 4; ++i) {
#pragma unroll
            for (int j = 0; j < 4; ++j) {
                const float4 a = A[f][i], b = Bv[f][j];
                const float dx = a.x - b.x, dy = a.y - b.y;
                const float dz = a.z - b.z, dw = a.w - b.w;
                c[f * 16 + i * 4 + j] = dx * dx + dy * dy + dz * dz + dw * dw;
            }
        }
    }
#pragma unroll
    for (int v = 48; v < 64; ++v) c[v] = 0.f;

    // ---- recursive-halving reduce: lane L ends with sum_lanes(c[L]) ----
    // step s: keep values whose index-bit s equals lane-bit s; 63 shuffles.
#pragma unroll
    for (int s = 0; s < 6; ++s) {
        const int bit = 1 << s;
        const bool hi = (lane & bit) != 0;
#pragma unroll
        for (int k = 0; k < 32; ++k) {
            if (k < (32 >> s)) {
                const float lo_v = c[2 * k], hi_v = c[2 * k + 1];
                const float send = hi ? lo_v : hi_v;
                const float recv = __shfl_xor(send, bit, 64);
                c[k] = (hi ? hi_v : lo_v) + recv;
            }
        }
    }
    const float red = c[0];  // lane v holds d2 sum for value index v (<48)

    // ---- lane l computes loss of group-row r = l&7 (8x redundant mask) ----
    const int r = lane & 7;
    const bool isRow = r < 4;           // half0 row r : half1 col r-4
    float d2[3][4];
#pragma unroll
    for (int f = 0; f < 3; ++f) {
#pragma unroll
        for (int t = 0; t < 4; ++t) {
            const int src = f * 16 + (isRow ? (r * 4 + t) : (t * 4 + (r - 4)));
            d2[f][t] = __shfl(red, src, 64);
        }
    }
    float loss = row_loss(d2);
    loss = (lane < 8) ? loss : 0.f;
#pragma unroll
    for (int m = 32; m >= 1; m >>= 1) loss += __shfl_xor(loss, m, 64);

    if (lane == 0) {
        atomicAdd(ws, loss);
        __threadfence();
        const unsigned old = atomicAdd((unsigned*)(ws + 1), 1u);
        if (old == (unsigned)(nblocks - 1)) {
            const float total = atomicAdd(ws, 0.0f);  // coherent read
            out[0] = total * inv_n;
        }
    }
}

extern "C" void kernel_launch(void* const* d_in, const int* in_sizes, int n_in,
                              void* d_out, int out_size, void* d_ws,
                              size_t ws_size, hipStream_t stream) {
    const float* f0 = (const float*)d_in[0];
    const float* f1 = (const float*)d_in[1];
    const float* f2 = (const float*)d_in[2];
    const int* target = (const int*)d_in[3];
    const int N = in_sizes[3];        // 4096
    const int nblocks = N / 8;        // one wave-block per id-group (512)
    hipMemsetAsync(d_ws, 0, 16, stream);  // zero {acc, counter}
    cmrr_fused<<<nblocks, 64, 0, stream>>>(f0, f1, f2, target, (float*)d_ws,
                                           (float*)d_out, N, 1.0f / (float)N,
                                           nblocks);
}

// Round 4
// 74.898 us; speedup vs baseline: 1.1710x; 1.1489x over previous
//
#include <hip/hip_runtime.h>
#include <hip/hip_bf16.h>

// P=512, K=4, D=256, N=4096. One WAVE per id-group g: half0 rows 4g..4g+3,
// half1 rows N/2+4id..+3 (id=target[4g]). All 8 rows' positive distances are
// one 4x4 cross-half matrix. Zero barriers, zero LDS, zero atomics: each
// block writes a disjoint partial; a 1-wave kernel reduces 512 floats.

__device__ __forceinline__ void soft_rank4(const float d2[4], float r[4]) {
    float th[4]; int p[4] = {0, 1, 2, 3};
#pragma unroll
    for (int t = 0; t < 4; ++t) th[t] = 0.5f * sqrtf(fmaxf(d2[t], 1e-12f));
#define CSWAP(a, b)                                                           \
    if (th[a] < th[b]) {                                                      \
        float tt = th[a]; th[a] = th[b]; th[b] = tt;                          \
        int tp = p[a]; p[a] = p[b]; p[b] = tp;                                \
    }
    CSWAP(0, 1) CSWAP(1, 2) CSWAP(2, 3) CSWAP(0, 1) CSWAP(1, 2) CSWAP(0, 1)
#undef CSWAP
    const float logW[4][4] = {
        {1.3862944f, 1.9459101f, 2.1972246f, 2.3025851f},
        {0.f,        1.0986123f, 1.6094379f, 1.7917595f},
        {0.f,        0.f,        0.6931472f, 1.0986123f},
        {0.f,        0.f,        0.f,        0.f}};
    float B[4][4];
#pragma unroll
    for (int i = 0; i < 4; ++i) {
        float run = 0.f;
#pragma unroll
        for (int j = 0; j < 4; ++j) {
            if (j >= i) {
                run += __expf(th[j] - th[i]);
                B[i][j] = th[i] + __logf(run) - logW[i][j];
            }
        }
    }
    float rs[4];
#pragma unroll
    for (int k = 0; k < 4; ++k) {
        float dual = 1e30f;
#pragma unroll
        for (int i = 0; i < 4; ++i) {
            if (i <= k) {
                float mx = -1e30f;
#pragma unroll
                for (int j = 0; j < 4; ++j)
                    if (j >= k) mx = fmaxf(mx, B[i][j]);
                dual = fminf(dual, mx);
            }
        }
        rs[k] = __expf(th[k] - dual);
    }
#pragma unroll
    for (int t = 0; t < 4; ++t) {
        float v = rs[3];
        v = (p[2] == t) ? rs[2] : v;
        v = (p[1] == t) ? rs[1] : v;
        v = (p[0] == t) ? rs[0] : v;
        r[t] = v;
    }
}

__device__ __forceinline__ float spearman4(const float a[4], const float b[4]) {
    float ma = 0.25f * (a[0] + a[1] + a[2] + a[3]);
    float mb = 0.25f * (b[0] + b[1] + b[2] + b[3]);
    float sab = 0.f, saa = 0.f, sbb = 0.f;
#pragma unroll
    for (int t = 0; t < 4; ++t) {
        float x = a[t] - ma, y = b[t] - mb;
        sab += x * y; saa += x * x; sbb += y * y;
    }
    return sab * rsqrtf(saa * sbb);
}

__device__ __forceinline__ float row_loss(const float d2a[3][4]) {
    float ranks[3][4];
#pragma unroll
    for (int f = 0; f < 3; ++f) soft_rank4(d2a[f], ranks[f]);
    const float c01 = spearman4(ranks[0], ranks[1]);
    const float c02 = spearman4(ranks[0], ranks[2]);
    const float c12 = spearman4(ranks[1], ranks[2]);
    return (c01 + c02 + c12 + 3.f) * (0.5f / 3.f);
}

__global__ __launch_bounds__(64) void cmrr_main(
        const float* __restrict__ f0, const float* __restrict__ f1,
        const float* __restrict__ f2, const int* __restrict__ target,
        float* __restrict__ partials, int N) {
    const float* F[3] = {f0, f1, f2};
    const int g = blockIdx.x;
    const int lane = threadIdx.x;       // block == 1 wave
    const int half = N >> 1;
    const int id = target[4 * g];       // uniform -> scalar load
    const int jbase = half + 4 * id;

    // ---- 24 independent float4 loads: 8 rows x 3 features, lane = dim/4 ----
    float4 A[3][4], Bv[3][4];
#pragma unroll
    for (int f = 0; f < 3; ++f) {
        const float4* pa = (const float4*)(F[f] + (size_t)(4 * g) * 256);
#pragma unroll
        for (int i = 0; i < 4; ++i) A[f][i] = pa[i * 64 + lane];
    }
#pragma unroll
    for (int f = 0; f < 3; ++f) {
        const float4* pb = (const float4*)(F[f] + (size_t)jbase * 256);
#pragma unroll
        for (int j = 0; j < 4; ++j) Bv[f][j] = pb[j * 64 + lane];
    }

    // ---- 48 per-lane distance partials (value idx v = f*16 + i*4 + j) ----
    float c[64];
#pragma unroll
    for (int f = 0; f < 3; ++f) {
#pragma unroll
        for (int i = 0; i < 4; ++i) {
#pragma unroll
            for (int j = 0; j < 4; ++j) {
                const float4 a = A[f][i], b = Bv[f][j];
                const float dx = a.x - b.x, dy = a.y - b.y;
                const float dz = a.z - b.z, dw = a.w - b.w;
                c[f * 16 + i * 4 + j] = dx * dx + dy * dy + dz * dz + dw * dw;
            }
        }
    }
#pragma unroll
    for (int v = 48; v < 64; ++v) c[v] = 0.f;

    // ---- recursive-halving reduce: lane v ends with sum_lanes(c[v]) ----
#pragma unroll
    for (int s = 0; s < 6; ++s) {
        const int bit = 1 << s;
        const bool hi = (lane & bit) != 0;
#pragma unroll
        for (int k = 0; k < 32; ++k) {
            if (k < (32 >> s)) {
                const float lo_v = c[2 * k], hi_v = c[2 * k + 1];
                const float send = hi ? lo_v : hi_v;
                const float recv = __shfl_xor(send, bit, 64);
                c[k] = (hi ? hi_v : lo_v) + recv;
            }
        }
    }
    const float red = c[0];

    // ---- lane l computes loss of group-row r = l&7 (lanes 8..63 masked) ----
    const int r = lane & 7;
    const bool isRow = r < 4;           // half0 row r : half1 col r-4
    float d2[3][4];
#pragma unroll
    for (int f = 0; f < 3; ++f) {
#pragma unroll
        for (int t = 0; t < 4; ++t) {
            const int src = f * 16 + (isRow ? (r * 4 + t) : (t * 4 + (r - 4)));
            d2[f][t] = __shfl(red, src, 64);
        }
    }
    float loss = row_loss(d2);
    loss = (lane < 8) ? loss : 0.f;
#pragma unroll
    for (int m = 32; m >= 1; m >>= 1) loss += __shfl_xor(loss, m, 64);

    if (lane == 0) partials[g] = loss;  // disjoint write, no atomics
}

__global__ __launch_bounds__(64) void cmrr_reduce(
        const float* __restrict__ partials, float* __restrict__ out,
        int nparts, float inv_n) {
    float s = 0.f;
    for (int i = threadIdx.x; i < nparts; i += 64) s += partials[i];
#pragma unroll
    for (int m = 32; m >= 1; m >>= 1) s += __shfl_xor(s, m, 64);
    if (threadIdx.x == 0) out[0] = s * inv_n;
}

extern "C" void kernel_launch(void* const* d_in, const int* in_sizes, int n_in,
                              void* d_out, int out_size, void* d_ws,
                              size_t ws_size, hipStream_t stream) {
    const float* f0 = (const float*)d_in[0];
    const float* f1 = (const float*)d_in[1];
    const float* f2 = (const float*)d_in[2];
    const int* target = (const int*)d_in[3];
    const int N = in_sizes[3];        // 4096
    const int ngroups = N / 8;        // 512 wave-blocks
    float* parts = (float*)d_ws;
    cmrr_main<<<ngroups, 64, 0, stream>>>(f0, f1, f2, target, parts, N);
    cmrr_reduce<<<1, 64, 0, stream>>>(parts, (float*)d_out, ngroups,
                                      1.0f / (float)N);
}